// Round 6
// baseline (32.434 us; speedup 1.0000x reference)
//
#include <hip/hip_runtime.h>
#include <math.h>

#define CH  4096          // b-chunk staged in LDS (SoA: 16KB t_bits + 16KB ex)
#define TPB 256           // 4 waves
#define APW 4             // a-values per wave
#define APB 16            // 4 waves * 4

// partials[blk*4 + {0,1,2,3}] = {lik, rank, pair_cnt, n_events}
// counter: int at partials + nblocks*4 (memset to 0 by host each launch)

__device__ __forceinline__ void proc8(const uint4 tt0, const uint4 tt1,
                                      const float4 xx0, const float4 xx1,
                                      const unsigned int taj,
                                      float& sgt_, int& cnt_) {
    bool g;
    g = (tt0.x > taj); sgt_ += g ? xx0.x : 0.f; cnt_ += __popcll(__ballot(g));
    g = (tt0.y > taj); sgt_ += g ? xx0.y : 0.f; cnt_ += __popcll(__ballot(g));
    g = (tt0.z > taj); sgt_ += g ? xx0.z : 0.f; cnt_ += __popcll(__ballot(g));
    g = (tt0.w > taj); sgt_ += g ? xx0.w : 0.f; cnt_ += __popcll(__ballot(g));
    g = (tt1.x > taj); sgt_ += g ? xx1.x : 0.f; cnt_ += __popcll(__ballot(g));
    g = (tt1.y > taj); sgt_ += g ? xx1.y : 0.f; cnt_ += __popcll(__ballot(g));
    g = (tt1.z > taj); sgt_ += g ? xx1.z : 0.f; cnt_ += __popcll(__ballot(g));
    g = (tt1.w > taj); sgt_ += g ? xx1.w : 0.f; cnt_ += __popcll(__ballot(g));
}

__global__ __launch_bounds__(TPB)
void pair_scan(const float* __restrict__ t,
               const float* __restrict__ r,
               const int*   __restrict__ e,
               double* __restrict__ partials,
               int* __restrict__ counter,
               float* __restrict__ out,
               int n, int nblocks) {
    __shared__ __align__(16) unsigned int st[CH];   // t bits
    __shared__ __align__(16) float        sx[CH];   // exp(r)
    __shared__ double red[4][3];
    __shared__ float  swsum[4];
    __shared__ int    swev[4];
    __shared__ int    slast;

    const int tid  = threadIdx.x;
    const int lane = tid & 63;
    const int wid  = tid >> 6;

    // this wave's 4 a-values (wave-uniform)
    const int a0 = blockIdx.x * APB + wid * APW;
    unsigned int ta[APW];
    float ra[APW];
    int   ea[APW];
#pragma unroll
    for (int j = 0; j < APW; ++j) {
        const int a = a0 + j;
        const bool ok = (a < n);
        const int ai = ok ? a : 0;
        ta[j] = __float_as_uint(t[ai]);   // t >= 0 -> u32 order == float order
        ra[j] = r[ai];
        ea[j] = ok ? e[ai] : 0;
    }

    float sgt[APW] = {0.f, 0.f, 0.f, 0.f};
    int   cnt[APW] = {0, 0, 0, 0};
    float xsum  = 0.f;
    int   evsum = 0;

    const int nch = (n + CH - 1) / CH;
    for (int c = 0; c < nch; ++c) {
        const int base = c * CH;
        // ---- stage chunk SoA (pad inert: t_bits=0, ex=0) ----
#pragma unroll
        for (int k = 0; k < CH / (TPB * 4); ++k) {
            const int li = tid * 4 + k * TPB * 4;
            const int gi = base + li;
            uint4  tb;
            float4 xb;
            if (gi + 3 < n) {
                const float4 tv = *(const float4*)(t + gi);
                const float4 rv = *(const float4*)(r + gi);
                const int4   ev = *(const int4*)(e + gi);
                tb = make_uint4(__float_as_uint(tv.x), __float_as_uint(tv.y),
                                __float_as_uint(tv.z), __float_as_uint(tv.w));
                xb = make_float4(__expf(rv.x), __expf(rv.y), __expf(rv.z), __expf(rv.w));
                evsum += (ev.x == 1) + (ev.y == 1) + (ev.z == 1) + (ev.w == 1);
                xsum  += xb.x + xb.y + xb.z + xb.w;
            } else {
                float tvv[4], xvv[4];
#pragma unroll
                for (int m = 0; m < 4; ++m) {
                    const int g = gi + m;
                    if (g < n) {
                        tvv[m] = t[g];
                        xvv[m] = __expf(r[g]);
                        evsum += (e[g] == 1);
                        xsum  += xvv[m];
                    } else { tvv[m] = 0.f; xvv[m] = 0.f; }
                }
                tb = make_uint4(__float_as_uint(tvv[0]), __float_as_uint(tvv[1]),
                                __float_as_uint(tvv[2]), __float_as_uint(tvv[3]));
                xb = make_float4(xvv[0], xvv[1], xvv[2], xvv[3]);
            }
            *(uint4*)(st + li)  = tb;
            *(float4*)(sx + li) = xb;
        }
        __syncthreads();

        // ---- scan: 512 b per wave-iter, double-buffered register loads ----
        const int o0 = lane * 4;
        uint4  ct0 = *(const uint4*)(st + o0);
        uint4  ct1 = *(const uint4*)(st + o0 + 256);
        float4 cx0 = *(const float4*)(sx + o0);
        float4 cx1 = *(const float4*)(sx + o0 + 256);
        for (int it = 0; it < CH / 512; ++it) {
            uint4  nt0 = ct0, nt1 = ct1;
            float4 nx0 = cx0, nx1 = cx1;
            if (it + 1 < CH / 512) {
                const int o = o0 + (it + 1) * 512;
                nt0 = *(const uint4*)(st + o);
                nt1 = *(const uint4*)(st + o + 256);
                nx0 = *(const float4*)(sx + o);
                nx1 = *(const float4*)(sx + o + 256);
            }
#pragma unroll
            for (int j = 0; j < APW; ++j)
                proc8(ct0, ct1, cx0, cx1, ta[j], sgt[j], cnt[j]);
            ct0 = nt0; ct1 = nt1; cx0 = nx0; cx1 = nx1;
        }
        __syncthreads();   // safe to restage next chunk
    }

    // ---- wave butterflies (cnt already wave-uniform via ballot) ----
#pragma unroll
    for (int off = 32; off > 0; off >>= 1) {
#pragma unroll
        for (int j = 0; j < APW; ++j)
            sgt[j] += __shfl_xor(sgt[j], off);
        xsum  += __shfl_xor(xsum, off);
        evsum += __shfl_xor(evsum, off);
    }
    if (lane == 0) { swsum[wid] = xsum; swev[wid] = evsum; }
    __syncthreads();

    const float S  = swsum[0] + swsum[1] + swsum[2] + swsum[3];
    const int   EV = swev[0] + swev[1] + swev[2] + swev[3];

    if (lane == 0) {
        double lik = 0.0, rnk = 0.0, pc = 0.0;
#pragma unroll
        for (int j = 0; j < APW; ++j) {
            if (ea[j] == 1) {
                // ssf = sum over {t_b <= t_a} = S - sgt; exact lower bound: own term
                float ssf = S - sgt[j];
                ssf = fmaxf(ssf, __expf(ra[j]));
                lik += (double)(ra[j] - __logf(ssf));
                rnk += (double)(__expf(-ra[j]) * sgt[j]);
                pc  += (double)cnt[j];
            }
        }
        red[wid][0] = lik; red[wid][1] = rnk; red[wid][2] = pc;
    }
    __syncthreads();
    if (tid == 0) {
        partials[blockIdx.x * 4 + 0] = red[0][0] + red[1][0] + red[2][0] + red[3][0];
        partials[blockIdx.x * 4 + 1] = red[0][1] + red[1][1] + red[2][1] + red[3][1];
        partials[blockIdx.x * 4 + 2] = red[0][2] + red[1][2] + red[2][2] + red[3][2];
        partials[blockIdx.x * 4 + 3] = (double)EV;
        __threadfence();                       // release partials
        const int old = atomicAdd(counter, 1); // device-scope
        slast = (old == nblocks - 1) ? 1 : 0;
    }
    __syncthreads();

    // ---- last block: grid-wide reduce + final scalar (deterministic order) ----
    if (slast) {
        __threadfence();                       // acquire others' partials
        double lik = 0.0, rnk = 0.0, pc = 0.0;
        for (int i = tid; i < nblocks; i += TPB) {
            lik += partials[i * 4 + 0];
            rnk += partials[i * 4 + 1];
            pc  += partials[i * 4 + 2];
        }
        double* dl = (double*)st;              // reuse 32KB LDS: 3*256 doubles = 6KB
        dl[tid]       = lik;
        dl[256 + tid] = rnk;
        dl[512 + tid] = pc;
        __syncthreads();
        for (int s = 128; s > 0; s >>= 1) {
            if (tid < s) {
                dl[tid]       += dl[tid + s];
                dl[256 + tid] += dl[256 + tid + s];
                dl[512 + tid] += dl[512 + tid + s];
            }
            __syncthreads();
        }
        if (tid == 0) {
            const float nev  = (float)EV;      // this block's full-range event count
            const float likf = (float)dl[0];
            const float rnkf = (float)dl[256];
            const float pcf  = (float)dl[512];
            const float likelihood_loss = -likf / (nev + 1e-8f);
            const float ranking_loss = (pcf > 0.f) ? (rnkf / fmaxf(pcf, 1.f)) : rnkf;
            out[0] = likelihood_loss + 0.2f * ranking_loss;
        }
    }
}

extern "C" void kernel_launch(void* const* d_in, const int* in_sizes, int n_in,
                              void* d_out, int out_size, void* d_ws, size_t ws_size,
                              hipStream_t stream) {
    const float* risk   = (const float*)d_in[0];
    const float* times  = (const float*)d_in[1];
    const int*   events = (const int*)d_in[2];
    float* out = (float*)d_out;
    const int n = in_sizes[0];

    const int nblocks = (n + APB - 1) / APB;
    double* partials = (double*)d_ws;
    int* counter = (int*)((char*)d_ws + (size_t)nblocks * 4 * sizeof(double));

    hipMemsetAsync(counter, 0, sizeof(int), stream);
    pair_scan<<<nblocks, TPB, 0, stream>>>(times, risk, events,
                                           partials, counter, out, n, nblocks);
}

// Round 7
// 21.670 us; speedup vs baseline: 1.4967x; 1.4967x over previous
//
#include <hip/hip_runtime.h>
#include <math.h>

#define CH  4096          // b-chunk staged in LDS (SoA: 16KB t_bits + 16KB ex)
#define TPB 256           // 4 waves
#define APW 4             // a-values per wave
#define APB 16            // 4 waves * 4

// partials[blk*4 + {0,1,2,3}] = {lik, rank, pair_cnt, n_events}

__device__ __forceinline__ void proc8(const uint4 tt0, const uint4 tt1,
                                      const float4 xx0, const float4 xx1,
                                      const unsigned int taj,
                                      float& sgt_, int& cnt_) {
    bool g;
    g = (tt0.x > taj); sgt_ += g ? xx0.x : 0.f; cnt_ += __popcll(__ballot(g));
    g = (tt0.y > taj); sgt_ += g ? xx0.y : 0.f; cnt_ += __popcll(__ballot(g));
    g = (tt0.z > taj); sgt_ += g ? xx0.z : 0.f; cnt_ += __popcll(__ballot(g));
    g = (tt0.w > taj); sgt_ += g ? xx0.w : 0.f; cnt_ += __popcll(__ballot(g));
    g = (tt1.x > taj); sgt_ += g ? xx1.x : 0.f; cnt_ += __popcll(__ballot(g));
    g = (tt1.y > taj); sgt_ += g ? xx1.y : 0.f; cnt_ += __popcll(__ballot(g));
    g = (tt1.z > taj); sgt_ += g ? xx1.z : 0.f; cnt_ += __popcll(__ballot(g));
    g = (tt1.w > taj); sgt_ += g ? xx1.w : 0.f; cnt_ += __popcll(__ballot(g));
}

__global__ __launch_bounds__(TPB)
void pair_scan(const float* __restrict__ t,
               const float* __restrict__ r,
               const int*   __restrict__ e,
               double* __restrict__ partials, int n) {
    __shared__ __align__(16) unsigned int st[CH];   // t bits
    __shared__ __align__(16) float        sx[CH];   // exp(r)
    __shared__ double red[4][3];
    __shared__ float  swsum[4];
    __shared__ int    swev[4];

    const int tid  = threadIdx.x;
    const int lane = tid & 63;
    const int wid  = tid >> 6;

    // this wave's 4 a-values (wave-uniform)
    const int a0 = blockIdx.x * APB + wid * APW;
    unsigned int ta[APW];
    float ra[APW];
    int   ea[APW];
#pragma unroll
    for (int j = 0; j < APW; ++j) {
        const int a = a0 + j;
        const bool ok = (a < n);
        const int ai = ok ? a : 0;
        ta[j] = __float_as_uint(t[ai]);   // t >= 0 -> u32 order == float order
        ra[j] = r[ai];
        ea[j] = ok ? e[ai] : 0;
    }

    float sgt[APW] = {0.f, 0.f, 0.f, 0.f};
    int   cnt[APW] = {0, 0, 0, 0};
    float xsum  = 0.f;
    int   evsum = 0;

    const int nch = (n + CH - 1) / CH;
    for (int c = 0; c < nch; ++c) {
        const int base = c * CH;
        // ---- stage chunk SoA (pad inert: t_bits=0, ex=0) ----
#pragma unroll
        for (int k = 0; k < CH / (TPB * 4); ++k) {
            const int li = tid * 4 + k * TPB * 4;
            const int gi = base + li;
            uint4  tb;
            float4 xb;
            if (gi + 3 < n) {
                const float4 tv = *(const float4*)(t + gi);
                const float4 rv = *(const float4*)(r + gi);
                const int4   ev = *(const int4*)(e + gi);
                tb = make_uint4(__float_as_uint(tv.x), __float_as_uint(tv.y),
                                __float_as_uint(tv.z), __float_as_uint(tv.w));
                xb = make_float4(__expf(rv.x), __expf(rv.y), __expf(rv.z), __expf(rv.w));
                evsum += (ev.x == 1) + (ev.y == 1) + (ev.z == 1) + (ev.w == 1);
                xsum  += xb.x + xb.y + xb.z + xb.w;
            } else {
                float tvv[4], xvv[4];
#pragma unroll
                for (int m = 0; m < 4; ++m) {
                    const int g = gi + m;
                    if (g < n) {
                        tvv[m] = t[g];
                        xvv[m] = __expf(r[g]);
                        evsum += (e[g] == 1);
                        xsum  += xvv[m];
                    } else { tvv[m] = 0.f; xvv[m] = 0.f; }
                }
                tb = make_uint4(__float_as_uint(tvv[0]), __float_as_uint(tvv[1]),
                                __float_as_uint(tvv[2]), __float_as_uint(tvv[3]));
                xb = make_float4(xvv[0], xvv[1], xvv[2], xvv[3]);
            }
            *(uint4*)(st + li)  = tb;
            *(float4*)(sx + li) = xb;
        }
        __syncthreads();

        // ---- scan: 512 b per wave-iter, double-buffered register loads ----
        const int o0 = lane * 4;
        uint4  ct0 = *(const uint4*)(st + o0);
        uint4  ct1 = *(const uint4*)(st + o0 + 256);
        float4 cx0 = *(const float4*)(sx + o0);
        float4 cx1 = *(const float4*)(sx + o0 + 256);
        for (int it = 0; it < CH / 512; ++it) {
            uint4  nt0 = ct0, nt1 = ct1;
            float4 nx0 = cx0, nx1 = cx1;
            if (it + 1 < CH / 512) {
                const int o = o0 + (it + 1) * 512;
                nt0 = *(const uint4*)(st + o);
                nt1 = *(const uint4*)(st + o + 256);
                nx0 = *(const float4*)(sx + o);
                nx1 = *(const float4*)(sx + o + 256);
            }
#pragma unroll
            for (int j = 0; j < APW; ++j)
                proc8(ct0, ct1, cx0, cx1, ta[j], sgt[j], cnt[j]);
            ct0 = nt0; ct1 = nt1; cx0 = nx0; cx1 = nx1;
        }
        __syncthreads();   // safe to restage next chunk
    }

    // ---- wave butterflies (cnt already wave-uniform via ballot) ----
#pragma unroll
    for (int off = 32; off > 0; off >>= 1) {
#pragma unroll
        for (int j = 0; j < APW; ++j)
            sgt[j] += __shfl_xor(sgt[j], off);
        xsum  += __shfl_xor(xsum, off);
        evsum += __shfl_xor(evsum, off);
    }
    if (lane == 0) { swsum[wid] = xsum; swev[wid] = evsum; }
    __syncthreads();

    const float S  = swsum[0] + swsum[1] + swsum[2] + swsum[3];
    const int   EV = swev[0] + swev[1] + swev[2] + swev[3];

    if (lane == 0) {
        double lik = 0.0, rnk = 0.0, pc = 0.0;
#pragma unroll
        for (int j = 0; j < APW; ++j) {
            if (ea[j] == 1) {
                // ssf = sum over {t_b <= t_a} = S - sgt; exact lower bound: own term
                float ssf = S - sgt[j];
                ssf = fmaxf(ssf, __expf(ra[j]));
                lik += (double)(ra[j] - __logf(ssf));
                rnk += (double)(__expf(-ra[j]) * sgt[j]);
                pc  += (double)cnt[j];
            }
        }
        red[wid][0] = lik; red[wid][1] = rnk; red[wid][2] = pc;
    }
    __syncthreads();
    if (tid == 0) {
        partials[blockIdx.x * 4 + 0] = red[0][0] + red[1][0] + red[2][0] + red[3][0];
        partials[blockIdx.x * 4 + 1] = red[0][1] + red[1][1] + red[2][1] + red[3][1];
        partials[blockIdx.x * 4 + 2] = red[0][2] + red[1][2] + red[2][2] + red[3][2];
        partials[blockIdx.x * 4 + 3] = (double)EV;
    }
}

// single-wave finalize: nblocks * 4 doubles
__global__ __launch_bounds__(64)
void finalize4_kernel(const double* __restrict__ partials,
                      int nblocks, float* __restrict__ out) {
    const int lane = threadIdx.x;
    double lik = 0.0, rnk = 0.0, pc = 0.0;
    for (int i = lane; i < nblocks; i += 64) {
        lik += partials[i * 4 + 0];
        rnk += partials[i * 4 + 1];
        pc  += partials[i * 4 + 2];
    }
#pragma unroll
    for (int off = 32; off > 0; off >>= 1) {
        lik += __shfl_xor(lik, off);
        rnk += __shfl_xor(rnk, off);
        pc  += __shfl_xor(pc,  off);
    }
    if (lane == 0) {
        const float nev  = (float)partials[3];   // block 0's full-range n_events
        const float likf = (float)lik;
        const float rnkf = (float)rnk;
        const float pcf  = (float)pc;
        const float likelihood_loss = -likf / (nev + 1e-8f);
        const float ranking_loss = (pcf > 0.f) ? (rnkf / fmaxf(pcf, 1.f)) : rnkf;
        out[0] = likelihood_loss + 0.2f * ranking_loss;
    }
}

extern "C" void kernel_launch(void* const* d_in, const int* in_sizes, int n_in,
                              void* d_out, int out_size, void* d_ws, size_t ws_size,
                              hipStream_t stream) {
    const float* risk   = (const float*)d_in[0];
    const float* times  = (const float*)d_in[1];
    const int*   events = (const int*)d_in[2];
    float* out = (float*)d_out;
    const int n = in_sizes[0];

    const int nblocks = (n + APB - 1) / APB;
    double* partials = (double*)d_ws;

    pair_scan<<<nblocks, TPB, 0, stream>>>(times, risk, events, partials, n);
    finalize4_kernel<<<1, 64, 0, stream>>>(partials, nblocks, out);
}

// Round 8
// 21.195 us; speedup vs baseline: 1.5302x; 1.0224x over previous
//
#include <hip/hip_runtime.h>
#include <math.h>

#define CH   8192         // staged table per chunk (SoA: 32KB t_bits + 32KB ex)
#define TPB  512          // 8 waves: waves 0-3 = a-owners, waves 4-7 mirror on half 2
#define APW  4            // a-values per a-wave
#define APB  16           // 4 a-waves * 4

// partials[blk*4 + {0,1,2,3}] = {lik, rank, pair_cnt, n_events}

__device__ __forceinline__ void proc8(const uint4 tt0, const uint4 tt1,
                                      const float4 xx0, const float4 xx1,
                                      const unsigned int taj,
                                      float& sgt_, int& cnt_) {
    bool g;
    g = (tt0.x > taj); sgt_ += g ? xx0.x : 0.f; cnt_ += g;
    g = (tt0.y > taj); sgt_ += g ? xx0.y : 0.f; cnt_ += g;
    g = (tt0.z > taj); sgt_ += g ? xx0.z : 0.f; cnt_ += g;
    g = (tt0.w > taj); sgt_ += g ? xx0.w : 0.f; cnt_ += g;
    g = (tt1.x > taj); sgt_ += g ? xx1.x : 0.f; cnt_ += g;
    g = (tt1.y > taj); sgt_ += g ? xx1.y : 0.f; cnt_ += g;
    g = (tt1.z > taj); sgt_ += g ? xx1.z : 0.f; cnt_ += g;
    g = (tt1.w > taj); sgt_ += g ? xx1.w : 0.f; cnt_ += g;
}

__global__ __launch_bounds__(TPB)
void pair_scan(const float* __restrict__ t,
               const float* __restrict__ r,
               const int*   __restrict__ e,
               double* __restrict__ partials, int n) {
    __shared__ __align__(16) unsigned int st[CH];   // t bits
    __shared__ __align__(16) float        sx[CH];   // exp(r)
    __shared__ float  swsgt[8][APW];
    __shared__ int    swcnt[8][APW];
    __shared__ float  swsum[8];
    __shared__ int    swev[8];
    __shared__ double red[4][3];
    __shared__ int    sEVtot;

    const int tid  = threadIdx.x;
    const int lane = tid & 63;
    const int wid  = tid >> 6;
    const int aw   = wid & 3;       // a-group index (shared by wid and wid+4)
    const int hb   = wid >> 2;      // which half of the b-range this wave scans

    // this a-group's 4 a-values (wave-uniform; identical in waves aw and aw+4)
    const int a0 = blockIdx.x * APB + aw * APW;
    unsigned int ta[APW];
    float ra[APW];
    int   ea[APW];
#pragma unroll
    for (int j = 0; j < APW; ++j) {
        const int a = a0 + j;
        const bool ok = (a < n);
        const int ai = ok ? a : 0;
        ta[j] = __float_as_uint(t[ai]);   // t >= 0 -> u32 order == float order
        ra[j] = r[ai];
        ea[j] = ok ? e[ai] : 0;
    }

    float sgt[APW] = {0.f, 0.f, 0.f, 0.f};
    int   cnt[APW] = {0, 0, 0, 0};
    float xsum  = 0.f;
    int   evsum = 0;

    const int nch = (n + CH - 1) / CH;
    for (int c = 0; c < nch; ++c) {
        const int base = c * CH;
        // ---- stage chunk SoA, all 8 waves (pad inert: t_bits=0, ex=0) ----
#pragma unroll
        for (int k = 0; k < CH / (TPB * 4); ++k) {
            const int li = tid * 4 + k * TPB * 4;
            const int gi = base + li;
            uint4  tb;
            float4 xb;
            if (gi + 3 < n) {
                const float4 tv = *(const float4*)(t + gi);
                const float4 rv = *(const float4*)(r + gi);
                const int4   ev = *(const int4*)(e + gi);
                tb = make_uint4(__float_as_uint(tv.x), __float_as_uint(tv.y),
                                __float_as_uint(tv.z), __float_as_uint(tv.w));
                xb = make_float4(__expf(rv.x), __expf(rv.y), __expf(rv.z), __expf(rv.w));
                evsum += (ev.x == 1) + (ev.y == 1) + (ev.z == 1) + (ev.w == 1);
                xsum  += xb.x + xb.y + xb.z + xb.w;
            } else {
                float tvv[4], xvv[4];
#pragma unroll
                for (int m = 0; m < 4; ++m) {
                    const int g = gi + m;
                    if (g < n) {
                        tvv[m] = t[g];
                        xvv[m] = __expf(r[g]);
                        evsum += (e[g] == 1);
                        xsum  += xvv[m];
                    } else { tvv[m] = 0.f; xvv[m] = 0.f; }
                }
                tb = make_uint4(__float_as_uint(tvv[0]), __float_as_uint(tvv[1]),
                                __float_as_uint(tvv[2]), __float_as_uint(tvv[3]));
                xb = make_float4(xvv[0], xvv[1], xvv[2], xvv[3]);
            }
            *(uint4*)(st + li)  = tb;
            *(float4*)(sx + li) = xb;
        }
        __syncthreads();

        // ---- scan THIS WAVE'S HALF of the chunk (512 b per iter, dbuf regs) ----
        const int o0 = hb * (CH / 2) + lane * 4;
        uint4  ct0 = *(const uint4*)(st + o0);
        uint4  ct1 = *(const uint4*)(st + o0 + 256);
        float4 cx0 = *(const float4*)(sx + o0);
        float4 cx1 = *(const float4*)(sx + o0 + 256);
        for (int it = 0; it < (CH / 2) / 512; ++it) {
            uint4  nt0 = ct0, nt1 = ct1;
            float4 nx0 = cx0, nx1 = cx1;
            if (it + 1 < (CH / 2) / 512) {
                const int o = o0 + (it + 1) * 512;
                nt0 = *(const uint4*)(st + o);
                nt1 = *(const uint4*)(st + o + 256);
                nx0 = *(const float4*)(sx + o);
                nx1 = *(const float4*)(sx + o + 256);
            }
#pragma unroll
            for (int j = 0; j < APW; ++j)
                proc8(ct0, ct1, cx0, cx1, ta[j], sgt[j], cnt[j]);
            ct0 = nt0; ct1 = nt1; cx0 = nx0; cx1 = nx1;
        }
        __syncthreads();   // safe to restage next chunk
    }

    // ---- per-wave butterflies ----
#pragma unroll
    for (int off = 32; off > 0; off >>= 1) {
#pragma unroll
        for (int j = 0; j < APW; ++j) {
            sgt[j] += __shfl_xor(sgt[j], off);
            cnt[j] += __shfl_xor(cnt[j], off);
        }
        xsum  += __shfl_xor(xsum, off);
        evsum += __shfl_xor(evsum, off);
    }
    if (lane == 0) {
#pragma unroll
        for (int j = 0; j < APW; ++j) { swsgt[wid][j] = sgt[j]; swcnt[wid][j] = cnt[j]; }
        swsum[wid] = xsum;
        swev[wid]  = evsum;
    }
    __syncthreads();

    // ---- combine the two half-scans; per-a epilogue on lane0 of waves 0-3 ----
    if (wid < 4 && lane == 0) {
        float S = 0.f;
        int   EV = 0;
#pragma unroll
        for (int w = 0; w < 8; ++w) { S += swsum[w]; EV += swev[w]; }
        double lik = 0.0, rnk = 0.0, pc = 0.0;
#pragma unroll
        for (int j = 0; j < APW; ++j) {
            const float sg = swsgt[wid][j] + swsgt[wid + 4][j];
            const int   cn = swcnt[wid][j] + swcnt[wid + 4][j];
            if (ea[j] == 1) {
                // ssf = sum over {t_b <= t_a} = S - sg; exact lower bound: own term
                float ssf = S - sg;
                ssf = fmaxf(ssf, __expf(ra[j]));
                lik += (double)(ra[j] - __logf(ssf));
                rnk += (double)(__expf(-ra[j]) * sg);
                pc  += (double)cn;
            }
        }
        red[wid][0] = lik; red[wid][1] = rnk; red[wid][2] = pc;
        if (wid == 0) sEVtot = EV;
    }
    __syncthreads();
    if (tid == 0) {
        partials[blockIdx.x * 4 + 0] = red[0][0] + red[1][0] + red[2][0] + red[3][0];
        partials[blockIdx.x * 4 + 1] = red[0][1] + red[1][1] + red[2][1] + red[3][1];
        partials[blockIdx.x * 4 + 2] = red[0][2] + red[1][2] + red[2][2] + red[3][2];
        partials[blockIdx.x * 4 + 3] = (double)sEVtot;
    }
}

// single-wave finalize: nblocks * 4 doubles
__global__ __launch_bounds__(64)
void finalize4_kernel(const double* __restrict__ partials,
                      int nblocks, float* __restrict__ out) {
    const int lane = threadIdx.x;
    double lik = 0.0, rnk = 0.0, pc = 0.0;
    for (int i = lane; i < nblocks; i += 64) {
        lik += partials[i * 4 + 0];
        rnk += partials[i * 4 + 1];
        pc  += partials[i * 4 + 2];
    }
#pragma unroll
    for (int off = 32; off > 0; off >>= 1) {
        lik += __shfl_xor(lik, off);
        rnk += __shfl_xor(rnk, off);
        pc  += __shfl_xor(pc,  off);
    }
    if (lane == 0) {
        const float nev  = (float)partials[3];   // block 0's full-range n_events
        const float likf = (float)lik;
        const float rnkf = (float)rnk;
        const float pcf  = (float)pc;
        const float likelihood_loss = -likf / (nev + 1e-8f);
        const float ranking_loss = (pcf > 0.f) ? (rnkf / fmaxf(pcf, 1.f)) : rnkf;
        out[0] = likelihood_loss + 0.2f * ranking_loss;
    }
}

extern "C" void kernel_launch(void* const* d_in, const int* in_sizes, int n_in,
                              void* d_out, int out_size, void* d_ws, size_t ws_size,
                              hipStream_t stream) {
    const float* risk   = (const float*)d_in[0];
    const float* times  = (const float*)d_in[1];
    const int*   events = (const int*)d_in[2];
    float* out = (float*)d_out;
    const int n = in_sizes[0];

    const int nblocks = (n + APB - 1) / APB;
    double* partials = (double*)d_ws;

    pair_scan<<<nblocks, TPB, 0, stream>>>(times, risk, events, partials, n);
    finalize4_kernel<<<1, 64, 0, stream>>>(partials, nblocks, out);
}